// Round 6
// baseline (55.371 us; speedup 1.0000x reference)
//
#include <hip/hip_runtime.h>
#include <math.h>

#define BB 32
#define MM 256
#define H2 32
#define NOUT 8

// sinh(t) up to sign (caller squares it). Series keeps relative accuracy for
// small t; exp formula for |t| >= 0.5.
__device__ __forceinline__ float sinh_mag(float t) {
    float a  = fabsf(t);
    float e  = __expf(a);
    float big = 0.5f * (e - __builtin_amdgcn_rcpf(e));
    float t2 = t * t;
    float small = t + t * t2 * (1.0f/6.0f + t2 * (1.0f/120.0f));
    return (a < 0.5f) ? small : big;
}

// sin(t) up to sign (caller squares it). Series for small t avoids the
// cos-cancellation region; hw sin elsewhere.
__device__ __forceinline__ float sin_mag(float t) {
    float a  = fabsf(t);
    float t2 = t * t;
    float small = t + t * t2 * (-1.0f/6.0f + t2 * (1.0f/120.0f));
    float big = __sinf(t);
    return (a < 0.5f) ? small : big;
}

__global__ __launch_bounds__(1024, 8) void interaction_kernel(
    const float* __restrict__ x, const int* __restrict__ mask,
    const float* __restrict__ W1, const float* __restrict__ b1,
    const float* __restrict__ W2, const float* __restrict__ b2,
    float* __restrict__ out)
{
    __shared__ float tile[NOUT * 4 * MM];   // 32 KB: [p][ii][j]

    // 2048 blocks; XCD-chunked swizzle (2048 % 8 == 0, bijective)
    const int bid = blockIdx.x;
    const int nb  = (bid & 7) * 256 + (bid >> 3);
    const int b   = nb >> 6;                // batch
    const int i0  = (nb & 63) << 2;         // first of 4 i-rows
    const int t   = threadIdx.x;            // 0..1023
    const int il  = t >> 8;                 // local i-row 0..3 (wave-uniform)
    const int j   = t & 255;

    const int i  = i0 + il;
    const int mi = mask[b * MM + i];        // wave-uniform

    float o[NOUT];
    if (mi) {
        // i-side (wave-uniform)
        const float eta_i = x[(b * MM + i) * 3 + 0];
        const float phi_i = x[(b * MM + i) * 3 + 1];
        const float lpt_i = x[(b * MM + i) * 3 + 2];
        // j-side per-thread
        const float eta_j = x[(b * MM + j) * 3 + 0];
        const float phi_j = x[(b * MM + j) * 3 + 1];
        const float lpt_j = x[(b * MM + j) * 3 + 2];
        const float mf    = mask[b * MM + j] ? 1.f : 0.f;

        const float dx  = eta_i - eta_j;
        const float dy  = phi_i - phi_j;
        const float dr2 = dx * dx + dy * dy;

        const float L   = (dr2 > 0.f) ? 0.5f * __logf(dr2) : 0.f;
        const float fdr = L;
        const float fkt = (dr2 > 0.f) ? fminf(lpt_i, lpt_j) + L : 0.f;

        // cosh(dx) - cos(dy) = 2*(sinh^2(dx/2) + sin^2(dy/2)) (cancellation-free)
        const float sh = sinh_mag(0.5f * dx);
        const float sn = sin_mag(0.5f * dy);
        const float c  = 2.0f * (sh * sh + sn * sn);
        const float fmass = (c > 0.f) ? __logf(2.0f * c) + lpt_i + lpt_j : 0.f;

        #pragma unroll
        for (int p = 0; p < NOUT; ++p) o[p] = b2[p];

        #pragma unroll
        for (int k = 0; k < H2; ++k) {
            float z = b1[k];
            z = fmaf(fmass, W1[k * 3 + 0], z);
            z = fmaf(fdr,   W1[k * 3 + 1], z);
            z = fmaf(fkt,   W1[k * 3 + 2], z);
            z = (z >= 0.f) ? z : 0.01f * z;   // leaky_relu
            #pragma unroll
            for (int p = 0; p < NOUT; ++p)
                o[p] = fmaf(z, W2[p * H2 + k], o[p]);
        }
        #pragma unroll
        for (int p = 0; p < NOUT; ++p) o[p] *= mf;
    } else {
        #pragma unroll
        for (int p = 0; p < NOUT; ++p) o[p] = 0.f;
    }

    // stage: tile[p*1024 + il*256 + j] == tile[p*1024 + t] (conflict-free)
    #pragma unroll
    for (int p = 0; p < NOUT; ++p) tile[p * 1024 + t] = o[p];
    __syncthreads();

    // store: per plane a 4KB contiguous chunk at out[(b*8+p)*64K + i0*256]
    const float4* tile4 = (const float4*)tile;
    float4* out4 = (float4*)out;
    #pragma unroll
    for (int q = t; q < 2048; q += 1024) {
        const int p   = q >> 8;          // 256 float4 per plane chunk
        const int idx = q & 255;
        out4[(size_t)(b * NOUT + p) * (MM * MM / 4) + i0 * (MM / 4) + idx] =
            tile4[q];
    }
}

extern "C" void kernel_launch(void* const* d_in, const int* in_sizes, int n_in,
                              void* d_out, int out_size, void* d_ws, size_t ws_size,
                              hipStream_t stream) {
    const float* x    = (const float*)d_in[0];
    const int*   mask = (const int*)d_in[1];
    const float* W1   = (const float*)d_in[2];
    const float* b1   = (const float*)d_in[3];
    const float* W2   = (const float*)d_in[4];
    const float* b2   = (const float*)d_in[5];
    float* out = (float*)d_out;

    dim3 grid(BB * MM / 4);
    dim3 block(1024);
    interaction_kernel<<<grid, block, 0, stream>>>(x, mask, W1, b1, W2, b2, out);
}

// Round 7
// 32.870 us; speedup vs baseline: 1.6845x; 1.6845x over previous
//
#include <hip/hip_runtime.h>
#include <math.h>

#define BB 32
#define MM 256
#define H2 32
#define NOUT 8

// sinh(t) up to sign (caller squares it). Series keeps relative accuracy for
// small t; exp formula for |t| >= 0.5.
__device__ __forceinline__ float sinh_mag(float t) {
    float a  = fabsf(t);
    float e  = __expf(a);
    float big = 0.5f * (e - __builtin_amdgcn_rcpf(e));
    float t2 = t * t;
    float small = t + t * t2 * (1.0f/6.0f + t2 * (1.0f/120.0f));
    return (a < 0.5f) ? small : big;
}

// sin(t) up to sign (caller squares it). Series for small t avoids the
// cos-cancellation region; hw sin elsewhere.
__device__ __forceinline__ float sin_mag(float t) {
    float a  = fabsf(t);
    float t2 = t * t;
    float small = t + t * t2 * (-1.0f/6.0f + t2 * (1.0f/120.0f));
    float big = __sinf(t);
    return (a < 0.5f) ? small : big;
}

__global__ __launch_bounds__(256) void interaction_kernel(
    const float* __restrict__ x, const int* __restrict__ mask,
    const float* __restrict__ W1, const float* __restrict__ b1,
    const float* __restrict__ W2, const float* __restrict__ b2,
    float* __restrict__ out)
{
    __shared__ int perm[MM];     // j-permutation: actives first
    __shared__ int wcnt[4];      // active count per wave

    // XCD-chunked swizzle: 8192 blocks, 8 XCDs
    const int bid = blockIdx.x;
    const int nb  = (bid & 7) * 1024 + (bid >> 3);
    const int b   = nb >> 8;
    const int i   = nb & 255;
    const int t   = threadIdx.x;
    const int w   = t >> 6;
    const int l   = t & 63;

    float* op = out + ((size_t)(b * NOUT)) * (MM * MM) + (size_t)i * MM;
    const int PSTRIDE = MM * MM;

    const int mi = mask[b * MM + i];   // block-uniform
    if (mi == 0) {                     // uniform exit (before barriers)
        #pragma unroll
        for (int p = 0; p < NOUT; ++p)
            __builtin_nontemporal_store(0.f, op + p * PSTRIDE + t);
        return;
    }

    // ---- j-compaction: actives first, order-preserving ----
    const int mj = mask[b * MM + t];
    const unsigned long long bm = __ballot(mj != 0);
    if (l == 0) wcnt[w] = __popcll(bm);
    __syncthreads();
    const int c0 = wcnt[0], c1 = wcnt[1], c2 = wcnt[2], c3 = wcnt[3];
    const int K  = c0 + c1 + c2 + c3;
    int abase = 0, ibase = K;          // bases for this wave's active/inactive
    if (w > 0) { abase += c0; ibase += 64 - c0; }
    if (w > 1) { abase += c1; ibase += 64 - c1; }
    if (w > 2) { abase += c2; ibase += 64 - c2; }
    const int lt = __popcll(bm & ((1ull << l) - 1ull));  // actives before me
    if (mj) perm[abase + lt] = t;
    else    perm[ibase + (l - lt)] = t;
    __syncthreads();

    const int j = perm[t];

    float o[NOUT];
    if (t < K) {
        // i-side (block-uniform -> scalar loads)
        const float eta_i = x[(b * MM + i) * 3 + 0];
        const float phi_i = x[(b * MM + i) * 3 + 1];
        const float lpt_i = x[(b * MM + i) * 3 + 2];
        // j-side (compacted gather)
        const float eta_j = x[(b * MM + j) * 3 + 0];
        const float phi_j = x[(b * MM + j) * 3 + 1];
        const float lpt_j = x[(b * MM + j) * 3 + 2];

        const float dx  = eta_i - eta_j;
        const float dy  = phi_i - phi_j;
        const float dr2 = dx * dx + dy * dy;

        const float L   = (dr2 > 0.f) ? 0.5f * __logf(dr2) : 0.f;
        const float fdr = L;
        const float fkt = (dr2 > 0.f) ? fminf(lpt_i, lpt_j) + L : 0.f;

        // cosh(dx) - cos(dy) = 2*(sinh^2(dx/2) + sin^2(dy/2)) (cancellation-free)
        const float sh = sinh_mag(0.5f * dx);
        const float sn = sin_mag(0.5f * dy);
        const float c  = 2.0f * (sh * sh + sn * sn);
        const float fmass = (c > 0.f) ? __logf(2.0f * c) + lpt_i + lpt_j : 0.f;

        #pragma unroll
        for (int p = 0; p < NOUT; ++p) o[p] = b2[p];

        #pragma unroll
        for (int k = 0; k < H2; ++k) {
            float z = b1[k];
            z = fmaf(fmass, W1[k * 3 + 0], z);
            z = fmaf(fdr,   W1[k * 3 + 1], z);
            z = fmaf(fkt,   W1[k * 3 + 2], z);
            z = (z >= 0.f) ? z : 0.01f * z;   // leaky_relu
            #pragma unroll
            for (int p = 0; p < NOUT; ++p)
                o[p] = fmaf(z, W2[p * H2 + k], o[p]);
        }
    } else {
        #pragma unroll
        for (int p = 0; p < NOUT; ++p) o[p] = 0.f;
    }

    #pragma unroll
    for (int p = 0; p < NOUT; ++p)
        __builtin_nontemporal_store(o[p], op + p * PSTRIDE + j);
}

extern "C" void kernel_launch(void* const* d_in, const int* in_sizes, int n_in,
                              void* d_out, int out_size, void* d_ws, size_t ws_size,
                              hipStream_t stream) {
    const float* x    = (const float*)d_in[0];
    const int*   mask = (const int*)d_in[1];
    const float* W1   = (const float*)d_in[2];
    const float* b1   = (const float*)d_in[3];
    const float* W2   = (const float*)d_in[4];
    const float* b2   = (const float*)d_in[5];
    float* out = (float*)d_out;

    dim3 grid(BB * MM);
    dim3 block(MM);
    interaction_kernel<<<grid, block, 0, stream>>>(x, mask, W1, b1, W2, b2, out);
}

// Round 8
// 24.359 us; speedup vs baseline: 2.2731x; 1.3494x over previous
//
#include <hip/hip_runtime.h>
#include <math.h>

#define BB 32
#define MM 256
#define H2 32
#define NOUT 8

// sinh(t) up to sign (caller squares it). Series keeps relative accuracy for
// small t; exp formula for |t| >= 0.5.
__device__ __forceinline__ float sinh_mag(float t) {
    float a  = fabsf(t);
    float e  = __expf(a);
    float big = 0.5f * (e - __builtin_amdgcn_rcpf(e));
    float t2 = t * t;
    float small = t + t * t2 * (1.0f/6.0f + t2 * (1.0f/120.0f));
    return (a < 0.5f) ? small : big;
}

// sin(t) up to sign (caller squares it). Series for small t avoids the
// cos-cancellation region; hw sin elsewhere.
__device__ __forceinline__ float sin_mag(float t) {
    float a  = fabsf(t);
    float t2 = t * t;
    float small = t + t * t2 * (-1.0f/6.0f + t2 * (1.0f/120.0f));
    float big = __sinf(t);
    return (a < 0.5f) ? small : big;
}

__global__ __launch_bounds__(256) void interaction_kernel(
    const float* __restrict__ x, const int* __restrict__ mask,
    const float* __restrict__ W1, const float* __restrict__ b1,
    const float* __restrict__ W2, const float* __restrict__ b2,
    float* __restrict__ out)
{
    __shared__ float o_lds[NOUT][MM];   // 8 KB un-permute + transpose buffer
    __shared__ int   perm[MM];          // j-permutation: actives first
    __shared__ int   wcnt[4];

    // XCD-chunked swizzle: 8192 blocks, 8 XCDs
    const int bid = blockIdx.x;
    const int nb  = (bid & 7) * 1024 + (bid >> 3);
    const int b   = nb >> 8;
    const int i   = nb & 255;
    const int t   = threadIdx.x;
    const int w   = t >> 6;
    const int l   = t & 63;

    float4* row4 = (float4*)(out + ((size_t)(b * NOUT)) * (MM * MM)
                                 + (size_t)i * MM);
    const int PS4 = MM * MM / 4;        // float4 plane stride

    const int mi = mask[b * MM + i];    // block-uniform
    if (mi == 0) {                      // uniform exit (before any barrier)
        const float4 z4 = make_float4(0.f, 0.f, 0.f, 0.f);
        row4[(size_t)w       * PS4 + l] = z4;
        row4[(size_t)(w + 4) * PS4 + l] = z4;
        return;
    }

    // ---- j-compaction: actives first, order-preserving ----
    const int mj = mask[b * MM + t];
    const unsigned long long bm = __ballot(mj != 0);
    if (l == 0) wcnt[w] = __popcll(bm);
    __syncthreads();
    const int c0 = wcnt[0], c1 = wcnt[1], c2 = wcnt[2], c3 = wcnt[3];
    const int K  = c0 + c1 + c2 + c3;
    int abase = 0, ibase = K;
    if (w > 0) { abase += c0; ibase += 64 - c0; }
    if (w > 1) { abase += c1; ibase += 64 - c1; }
    if (w > 2) { abase += c2; ibase += 64 - c2; }
    const int lt = __popcll(bm & ((1ull << l) - 1ull));
    if (mj) perm[abase + lt] = t;
    else    perm[ibase + (l - lt)] = t;
    __syncthreads();

    const int j = perm[t];

    float o[NOUT];
    if (t < K) {   // trailing waves skip uniformly; one wave diverges
        // i-side (block-uniform -> scalar loads)
        const float eta_i = x[(b * MM + i) * 3 + 0];
        const float phi_i = x[(b * MM + i) * 3 + 1];
        const float lpt_i = x[(b * MM + i) * 3 + 2];
        // j-side (compacted gather)
        const float eta_j = x[(b * MM + j) * 3 + 0];
        const float phi_j = x[(b * MM + j) * 3 + 1];
        const float lpt_j = x[(b * MM + j) * 3 + 2];

        const float dx  = eta_i - eta_j;
        const float dy  = phi_i - phi_j;
        const float dr2 = dx * dx + dy * dy;

        const float L   = (dr2 > 0.f) ? 0.5f * __logf(dr2) : 0.f;
        const float fdr = L;
        const float fkt = (dr2 > 0.f) ? fminf(lpt_i, lpt_j) + L : 0.f;

        // cosh(dx) - cos(dy) = 2*(sinh^2(dx/2) + sin^2(dy/2)) (cancellation-free)
        const float sh = sinh_mag(0.5f * dx);
        const float sn = sin_mag(0.5f * dy);
        const float c  = 2.0f * (sh * sh + sn * sn);
        const float fmass = (c > 0.f) ? __logf(2.0f * c) + lpt_i + lpt_j : 0.f;

        #pragma unroll
        for (int p = 0; p < NOUT; ++p) o[p] = b2[p];

        #pragma unroll
        for (int k = 0; k < H2; ++k) {
            float z = b1[k];
            z = fmaf(fmass, W1[k * 3 + 0], z);
            z = fmaf(fdr,   W1[k * 3 + 1], z);
            z = fmaf(fkt,   W1[k * 3 + 2], z);
            z = (z >= 0.f) ? z : 0.01f * z;   // leaky_relu
            #pragma unroll
            for (int p = 0; p < NOUT; ++p)
                o[p] = fmaf(z, W2[p * H2 + k], o[p]);
        }
    } else {
        #pragma unroll
        for (int p = 0; p < NOUT; ++p) o[p] = 0.f;
    }

    // un-permute through LDS (scatter is cheap here), then coalesced stores
    #pragma unroll
    for (int p = 0; p < NOUT; ++p) o_lds[p][j] = o[p];
    __syncthreads();

    row4[(size_t)w       * PS4 + l] = ((const float4*)o_lds[w    ])[l];
    row4[(size_t)(w + 4) * PS4 + l] = ((const float4*)o_lds[w + 4])[l];
}

extern "C" void kernel_launch(void* const* d_in, const int* in_sizes, int n_in,
                              void* d_out, int out_size, void* d_ws, size_t ws_size,
                              hipStream_t stream) {
    const float* x    = (const float*)d_in[0];
    const int*   mask = (const int*)d_in[1];
    const float* W1   = (const float*)d_in[2];
    const float* b1   = (const float*)d_in[3];
    const float* W2   = (const float*)d_in[4];
    const float* b2   = (const float*)d_in[5];
    float* out = (float*)d_out;

    dim3 grid(BB * MM);
    dim3 block(MM);
    interaction_kernel<<<grid, block, 0, stream>>>(x, mask, W1, b1, W2, b2, out);
}